// Round 15
// baseline (12124.058 us; speedup 1.0000x reference)
//
#include <hip/hip_runtime.h>
#include <hip/hip_bf16.h>

#define VOCAB 200000
#define EMB 256
#define HID 512
#define SEQ 8192
#define TOK 32768
#define TAGS 512
#define G4H 2048  // 4*HID
#define HBW 256   // h dwords per step per dir (packed bf16: 2 h per dword)

#define SENTP 0xFFFFFFFFu  // packed sentinel: bf16 NaN pair; finite h never produces it

typedef unsigned u2v __attribute__((ext_vector_type(2)));

__device__ __forceinline__ float sigmoidf_(float x) { return 1.0f / (1.0f + __expf(-x)); }
__device__ __forceinline__ float tanhf_(float x) { return 1.0f - 2.0f / (1.0f + __expf(2.0f * x)); }

__device__ __forceinline__ unsigned pack_bf16(float a, float b) {
  unsigned ua = __float_as_uint(a), ub = __float_as_uint(b);
  ua = (ua + 0x7FFFu + ((ua >> 16) & 1u)) >> 16;   // RNE
  ub = (ub + 0x7FFFu + ((ub >> 16) & 1u)) >> 16;
  return ua | (ub << 16);
}

// ------------- kernel 0: init (both h buffers + election table) --------------
__global__ void init_sentinel(unsigned* __restrict__ hbuf, int n,
                              unsigned* __restrict__ tab, int ntab) {
  int i = blockIdx.x * blockDim.x + threadIdx.x;
  int stride = gridDim.x * blockDim.x;
  for (int k = i; k < n; k += stride) hbuf[k] = SENTP;
  for (int k = i; k < ntab; k += stride) tab[k] = 0xFFFFFFFFu;
}

// ---------------- kernel 1: embedding bag (sum pool per sorted segment) ------
__global__ __launch_bounds__(256) void embed_pool(
    const float* __restrict__ emb, const int* __restrict__ ids,
    const int* __restrict__ seg, float* __restrict__ out) {
  int s = blockIdx.x;
  int d = threadIdx.x;  // 256 = EMB
  int lo = 0, hi = TOK;
  while (lo < hi) { int m = (lo + hi) >> 1; if (seg[m] < s) lo = m + 1; else hi = m; }
  int start = lo;
  hi = TOK;
  while (lo < hi) { int m = (lo + hi) >> 1; if (seg[m] < s + 1) lo = m + 1; else hi = m; }
  int end = lo;
  float acc = 0.f;
  for (int tkn = start; tkn < end; ++tkn) {
    acc += emb[(long)ids[tkn] * EMB + d];
  }
  out[s * EMB + d] = acc;
}

// ---------------- kernel 2: xg = embeds @ w_ih^T + b  (both dirs) ------------
__global__ __launch_bounds__(256) void xg_gemm(
    const float* __restrict__ embeds,
    const float* __restrict__ w_ih_f, const float* __restrict__ b_f,
    const float* __restrict__ w_ih_b, const float* __restrict__ b_b,
    float* __restrict__ xg) {
  int dir = blockIdx.z;
  const float* W = dir ? w_ih_b : w_ih_f;
  const float* B = dir ? b_b : b_f;
  float* out = xg + (size_t)dir * SEQ * G4H;
  int j0 = blockIdx.x * 64, t0 = blockIdx.y * 64;
  __shared__ float As[64][65];
  __shared__ float Bs[64][65];
  int tid = threadIdx.x;
  int ty = tid >> 4, tx = tid & 15;
  float acc[4][4] = {};
  for (int kc = 0; kc < EMB; kc += 64) {
#pragma unroll
    for (int i = 0; i < 4; ++i) {
      int fi = tid * 4 + i;
      int r = fi >> 4, c4 = fi & 15;
      float4 a = *(const float4*)&embeds[(size_t)(t0 + r) * EMB + kc + c4 * 4];
      As[r][c4 * 4 + 0] = a.x; As[r][c4 * 4 + 1] = a.y;
      As[r][c4 * 4 + 2] = a.z; As[r][c4 * 4 + 3] = a.w;
      float4 b = *(const float4*)&W[(size_t)(j0 + r) * EMB + kc + c4 * 4];
      Bs[r][c4 * 4 + 0] = b.x; Bs[r][c4 * 4 + 1] = b.y;
      Bs[r][c4 * 4 + 2] = b.z; Bs[r][c4 * 4 + 3] = b.w;
    }
    __syncthreads();
#pragma unroll 8
    for (int kk = 0; kk < 64; ++kk) {
      float a[4], b[4];
#pragma unroll
      for (int i = 0; i < 4; ++i) a[i] = As[ty * 4 + i][kk];
#pragma unroll
      for (int i = 0; i < 4; ++i) b[i] = Bs[tx * 4 + i][kk];
#pragma unroll
      for (int i = 0; i < 4; ++i)
#pragma unroll
        for (int j = 0; j < 4; ++j) acc[i][j] = fmaf(a[i], b[j], acc[i][j]);
    }
    __syncthreads();
  }
#pragma unroll
  for (int i = 0; i < 4; ++i)
#pragma unroll
    for (int j = 0; j < 4; ++j)
      out[(size_t)(t0 + ty * 4 + i) * G4H + j0 + tx * 4 + j] = acc[i][j] + B[j0 + tx * 4 + j];
}

// -- kernel 3: LSTM scan, sc1-L2 poll, packed-bf16 h hand-off -----------------
// Protocol = rounds 12-14 (proven). Change: h travels as packed bf16
// (2 h/dword, 1KB/step/dir = 8 cache lines) -> poll L2 bandwidth and detect
// payload halve (R14's regression source), producer stores 1 dword/WG/step.
// Sentinel = 0xFFFFFFFF (bf16 NaN pair; finite h never produces it).
// Geometry = R14: 256 WGs/dir, 2 h/WG, 8 gate rows x 512 (16KB f32 LDS),
// 2 waves/SIMD. Weights stay f32; h unpacked with 1 shift / 1 and per value.
__global__ __launch_bounds__(64) void lstm_scan(
    const float* __restrict__ w_hh_f, const float* __restrict__ w_hh_b,
    const float* __restrict__ xg, unsigned* __restrict__ hb_fast_base,
    unsigned* __restrict__ hb_safe_base, unsigned* __restrict__ xcdtab,
    int force_slow) {
  int b = blockIdx.x;
  int sel = b & 7;
  if (sel >= 2) return;  // non-worker block
  int dir = sel;
  int Wk = b >> 3;  // 0..255
  const float* W = dir ? w_hh_b : w_hh_f;
  const float* xgd = xg + (size_t)dir * SEQ * G4H;
  unsigned* hb_fast = hb_fast_base + (size_t)dir * SEQ * HBW;
  unsigned* hb_safe = hb_safe_base + (size_t)dir * SEQ * HBW;

  int lane = threadIdx.x;  // 0..63
  const int hh = lane & 1;
  const int k0 = 2 * Wk;

  // publish my XCD id (HW_REG_XCC_ID = hwreg 20)
  int my_xcd = (int)(__builtin_amdgcn_s_getreg(20 | (31 << 11)) & 0xFu);
  if (lane == 0)
    __hip_atomic_store(&xcdtab[dir * 256 + Wk], (unsigned)my_xcd,
                       __ATOMIC_RELAXED, __HIP_MEMORY_SCOPE_AGENT);

  // stage W slice in LDS: 8 rows x 512 cols f32 = 16KB
  // LDS row r <-> global gate row 512*(r>>1) + k0 + (r&1)
  __shared__ float4 Wl[8 * 128];  // f4 idx = r*128 + hf*64 + l
  for (int idx = lane; idx < 8 * 128; idx += 64) {
    int r = idx >> 7, c4 = idx & 127;
    int gr = 512 * (r >> 1) + k0 + (r & 1);
    Wl[idx] = *(const float4*)&W[(size_t)gr * HID + 4 * c4];
  }
  __syncthreads();

  // election read-back (symmetric verdict): 256 producers per direction
  bool same = false;
  if (!force_slow) {
    bool ok = true;
#pragma unroll
    for (int pp = 0; pp < 4; ++pp) {
      int p = lane + 64 * pp;
      unsigned v = 0xFFFFFFFFu;
      for (int tries = 0; tries < (1 << 15); ++tries) {
        v = __hip_atomic_load(&xcdtab[dir * 256 + p], __ATOMIC_RELAXED,
                              __HIP_MEMORY_SCOPE_AGENT);
        if (v != 0xFFFFFFFFu) break;
        __builtin_amdgcn_s_sleep(4);
      }
      ok &= (v == (unsigned)my_xcd);
    }
    same = __all((int)ok);
  }

  // prologue: xg for the first step (in registers at loop entry)
  int tt0 = dir ? (SEQ - 1) : 0;
  const float* xr0 = xgd + (size_t)tt0 * G4H + k0 + hh;
  float xv0 = xr0[0], xv1 = xr0[512], xv2 = xr0[1024], xv3 = xr0[1536];

  float cst = 0.f;  // cell state for h[k0+hh] (redundant across parity lanes)

  for (int t = 0; t < SEQ; ++t) {
    int tt = dir ? (SEQ - 1 - t) : t;
    int pt = dir ? (tt + 1) : (tt - 1);
    // lane needs h cols {4l..4l+3} = dwords {2l,2l+1}; {256+4l..} = {128+2l,..}
    unsigned* srcF = hb_fast + (size_t)pt * HBW + 2 * lane;

    // A. issue first fast-poll sample before anything else
    u2v pa, pc;
    bool fastpoll = (t > 0) && same;
    if (fastpoll) {
      asm volatile(
          "global_load_dwordx2 %0, %2, off sc1\n\t"
          "global_load_dwordx2 %1, %2, off offset:512 sc1"
          : "=&v"(pa), "=&v"(pc)
          : "v"(srcF)
          : "memory");
    }

    // B. weight slice reads (LDS; independent of h; overlap poll RTT)
    float4 wl0[8], wl1[8];
#pragma unroll
    for (int r = 0; r < 8; ++r) {
      wl0[r] = Wl[r * 128 + lane];
      wl1[r] = Wl[r * 128 + 64 + lane];
    }

    // C. resolve h_prev (packed dwords d0..d3)
    unsigned d0, d1, d2, d3;
    if (t == 0) {
      d0 = d1 = d2 = d3 = 0u;  // bf16 pair (0,0)
    } else {
      if (fastpoll) {
        // rule-#18-safe deferred wait: tie poll regs + sched fence
        asm volatile("s_waitcnt vmcnt(0)" : "+v"(pa), "+v"(pc) :: "memory");
        __builtin_amdgcn_sched_barrier(0);
        d0 = pa.x; d1 = pa.y; d2 = pc.x; d3 = pc.y;
        bool ok = (d0 != SENTP) & (d1 != SENTP) & (d2 != SENTP) & (d3 != SENTP);
        bool got = __all((int)ok);
        for (int tries = 0; !got; ++tries) {
          u2v a, c;
          asm volatile(
              "global_load_dwordx2 %0, %2, off sc1\n\t"
              "global_load_dwordx2 %1, %2, off offset:512 sc1\n\t"
              "s_waitcnt vmcnt(0)"
              : "=&v"(a), "=&v"(c)
              : "v"(srcF)
              : "memory");
          __builtin_amdgcn_sched_barrier(0);
          d0 = a.x; d1 = a.y; d2 = c.x; d3 = c.y;
          ok = (d0 != SENTP) & (d1 != SENTP) & (d2 != SENTP) & (d3 != SENTP);
          got = __all((int)ok);
          if (!got && tries > 64) __builtin_amdgcn_s_sleep(2);
        }
      } else {
        // System-scope (L3) sentinel poll on hb_safe
        unsigned* src = hb_safe + (size_t)pt * HBW + 2 * lane;
        for (;;) {
          u2v a, c;
          asm volatile(
              "global_load_dwordx2 %0, %2, off sc0 sc1\n\t"
              "global_load_dwordx2 %1, %2, off offset:512 sc0 sc1\n\t"
              "s_waitcnt vmcnt(0)"
              : "=&v"(a), "=&v"(c)
              : "v"(src)
              : "memory");
          __builtin_amdgcn_sched_barrier(0);
          d0 = a.x; d1 = a.y; d2 = c.x; d3 = c.y;
          bool ok = (d0 != SENTP) & (d1 != SENTP) & (d2 != SENTP) & (d3 != SENTP);
          if (__all((int)ok)) break;
          __builtin_amdgcn_s_sleep(1);
        }
      }
    }
    // unpack: low half = even col, high half = odd col (exact bf16->f32)
    float4 h0, h1;
    h0.x = __uint_as_float(d0 << 16);
    h0.y = __uint_as_float(d0 & 0xFFFF0000u);
    h0.z = __uint_as_float(d1 << 16);
    h0.w = __uint_as_float(d1 & 0xFFFF0000u);
    h1.x = __uint_as_float(d2 << 16);
    h1.y = __uint_as_float(d2 & 0xFFFF0000u);
    h1.z = __uint_as_float(d3 << 16);
    h1.w = __uint_as_float(d3 & 0xFFFF0000u);

    // D. prefetch next step's xg (outside every poll's vmcnt window)
    int tn = (t + 1 < SEQ) ? (t + 1) : t;
    int ttn = dir ? (SEQ - 1 - tn) : tn;
    const float* xrn = xgd + (size_t)ttn * G4H + k0 + hh;
    float nx0 = xrn[0], nx1 = xrn[512], nx2 = xrn[1024], nx3 = xrn[1536];

    // E. matvec partials: acc[r] = sum over my 8 cols of W[r][c]*h[c]
    float acc[8];
#pragma unroll
    for (int r = 0; r < 8; ++r) {
      float4 wa = wl0[r];
      float4 wc = wl1[r];
      float a_ = wa.x * h0.x;
      a_ = fmaf(wa.y, h0.y, a_);
      a_ = fmaf(wa.z, h0.z, a_);
      a_ = fmaf(wa.w, h0.w, a_);
      a_ = fmaf(wc.x, h1.x, a_);
      a_ = fmaf(wc.y, h1.y, a_);
      a_ = fmaf(wc.z, h1.z, a_);
      a_ = fmaf(wc.w, h1.w, a_);
      acc[r] = a_;
    }

    // log-fold: 3 fold stages (xor1,2,4) + 3 butterflies (xor8,16,32);
    // ends with every lane holding the FULL sum of row (lane&7)
    float v4[4];
    {
      int b0 = lane & 1;
#pragma unroll
      for (int j = 0; j < 4; ++j) {
        float mine = b0 ? acc[2 * j + 1] : acc[2 * j];
        float oth  = b0 ? acc[2 * j] : acc[2 * j + 1];
        v4[j] = mine + __shfl_xor(oth, 1);
      }
    }
    float v2[2];
    {
      int b1 = (lane >> 1) & 1;
#pragma unroll
      for (int j = 0; j < 2; ++j) {
        float mine = b1 ? v2[0] * 0.f + (b1 ? v4[2 * j + 1] : v4[2 * j]) : v4[2 * j];
        // (kept simple below)
        mine = b1 ? v4[2 * j + 1] : v4[2 * j];
        float oth  = b1 ? v4[2 * j] : v4[2 * j + 1];
        v2[j] = mine + __shfl_xor(oth, 2);
      }
    }
    float v1;
    {
      int b2 = (lane >> 2) & 1;
      float mine = b2 ? v2[1] : v2[0];
      float oth  = b2 ? v2[0] : v2[1];
      v1 = mine + __shfl_xor(oth, 4);
      v1 += __shfl_xor(v1, 8);
      v1 += __shfl_xor(v1, 16);
      v1 += __shfl_xor(v1, 32);
    }

    // gather the 4 gate sums for my hh (row 2g+hh lives in lane 2g+hh)
    float si = __shfl(v1, hh + 0) + xv0;
    float sf = __shfl(v1, hh + 2) + xv1;
    float sg = __shfl(v1, hh + 4) + xv2;
    float so = __shfl(v1, hh + 6) + xv3;

    float iv = sigmoidf_(si), fv = sigmoidf_(sf), gv = tanhf_(sg), ov = sigmoidf_(so);
    cst = fv * cst + iv * gv;
    float h = ov * tanhf_(cst);

    // pack both h of this WG into one dword; lane 0 stores it
    float hodd = __shfl(h, 1);   // lane 1's value (hh=1)
    if (lane == 0) {
      unsigned packed = pack_bf16(h, hodd);
      hb_fast[(size_t)tt * HBW + Wk] = packed;        // plain -> local L2
      if (!same)
        __hip_atomic_store(hb_safe + (size_t)tt * HBW + Wk, packed,
                           __ATOMIC_RELAXED, __HIP_MEMORY_SCOPE_AGENT);
    }

    xv0 = nx0; xv1 = nx1; xv2 = nx2; xv3 = nx3;
  }
}

// ---------------- kernel 4: logits = h_cat @ w_out^T + b_out -----------------
// hbuf is packed bf16: [dir][SEQ][256] dwords (2 h per dword)
__global__ __launch_bounds__(256) void out_gemm(
    const unsigned* __restrict__ hbuf, const float* __restrict__ w_out,
    const float* __restrict__ b_out, float* __restrict__ out) {
  int j0 = blockIdx.x * 128, t0 = blockIdx.y * 64;
  __shared__ float hs[64][65];
  __shared__ float ws_[128][65];
  int tid = threadIdx.x;
  int ti = tid & 15, ji = tid >> 4;
  float acc[4][8] = {};
  for (int kc = 0; kc < 1024; kc += 64) {
    const unsigned* hsrc = (kc < 512) ? hbuf : (hbuf + (size_t)SEQ * HBW);
    int kbd = (kc & 511) >> 1;  // dword offset in row
#pragma unroll
    for (int j = 0; j < 8; ++j) {
      int idx = j * 256 + tid;        // 0..2047
      int r = idx >> 5, dw = idx & 31;
      unsigned u = hsrc[(size_t)(t0 + r) * HBW + kbd + dw];
      hs[r][dw * 2 + 0] = __uint_as_float(u << 16);
      hs[r][dw * 2 + 1] = __uint_as_float(u & 0xFFFF0000u);
    }
#pragma unroll
    for (int i = 0; i < 8; ++i) {
      int fi = tid * 8 + i;
      int r = fi >> 4, c4 = fi & 15;
      float4 v = *(const float4*)&w_out[(size_t)(j0 + r) * 1024 + kc + c4 * 4];
      ws_[r][c4 * 4 + 0] = v.x; ws_[r][c4 * 4 + 1] = v.y;
      ws_[r][c4 * 4 + 2] = v.z; ws_[r][c4 * 4 + 3] = v.w;
    }
    __syncthreads();
#pragma unroll 4
    for (int kk = 0; kk < 64; ++kk) {
      float a[4], b[8];
#pragma unroll
      for (int x = 0; x < 4; ++x) a[x] = hs[ti * 4 + x][kk];
#pragma unroll
      for (int y = 0; y < 8; ++y) b[y] = ws_[ji * 8 + y][kk];
#pragma unroll
      for (int x = 0; x < 4; ++x)
#pragma unroll
        for (int y = 0; y < 8; ++y) acc[x][y] = fmaf(a[x], b[y], acc[x][y]);
    }
    __syncthreads();
  }
#pragma unroll
  for (int x = 0; x < 4; ++x)
#pragma unroll
    for (int y = 0; y < 8; ++y)
      out[(size_t)(t0 + ti * 4 + x) * TAGS + j0 + ji * 8 + y] = acc[x][y] + b_out[j0 + ji * 8 + y];
}

// ---------------- kernel 5: row-wise log_softmax in place --------------------
__global__ __launch_bounds__(256) void logsoftmax(float* __restrict__ out) {
  int t = blockIdx.x;
  float* row = out + (size_t)t * TAGS;
  int tid = threadIdx.x;
  float a = row[tid], b = row[tid + 256];
  float m = fmaxf(a, b);
  m = fmaxf(m, __shfl_xor(m, 1));
  m = fmaxf(m, __shfl_xor(m, 2));
  m = fmaxf(m, __shfl_xor(m, 4));
  m = fmaxf(m, __shfl_xor(m, 8));
  m = fmaxf(m, __shfl_xor(m, 16));
  m = fmaxf(m, __shfl_xor(m, 32));
  __shared__ float redm[4];
  __shared__ float reds[4];
  int wv = tid >> 6;
  if ((tid & 63) == 0) redm[wv] = m;
  __syncthreads();
  m = fmaxf(fmaxf(redm[0], redm[1]), fmaxf(redm[2], redm[3]));
  float s = __expf(a - m) + __expf(b - m);
  s += __shfl_xor(s, 1);
  s += __shfl_xor(s, 2);
  s += __shfl_xor(s, 4);
  s += __shfl_xor(s, 8);
  s += __shfl_xor(s, 16);
  s += __shfl_xor(s, 32);
  if ((tid & 63) == 0) reds[wv] = s;
  __syncthreads();
  s = reds[0] + reds[1] + reds[2] + reds[3];
  float ls = m + __logf(s);
  row[tid] = a - ls;
  row[tid + 256] = b - ls;
}

extern "C" void kernel_launch(void* const* d_in, const int* in_sizes, int n_in,
                              void* d_out, int out_size, void* d_ws, size_t ws_size,
                              hipStream_t stream) {
  (void)in_sizes; (void)n_in; (void)out_size;
  const float* emb    = (const float*)d_in[0];
  const float* w_ih_f = (const float*)d_in[1];
  const float* w_hh_f = (const float*)d_in[2];
  const float* b_f    = (const float*)d_in[3];
  const float* w_ih_b = (const float*)d_in[4];
  const float* w_hh_b = (const float*)d_in[5];
  const float* b_b    = (const float*)d_in[6];
  const float* w_out  = (const float*)d_in[7];
  const float* b_out  = (const float*)d_in[8];
  const int*   ids    = (const int*)d_in[9];
  const int*   seg    = (const int*)d_in[10];
  float* out = (float*)d_out;

  char* ws = (char*)d_ws;
  float*    embeds  = (float*)ws;                                  // 8 MB
  float*    xg      = (float*)(ws + (8ll << 20));                  // 128 MB
  unsigned* hb_safe = (unsigned*)(ws + (136ll << 20));             // 8 MB (packed)
  size_t need = (152ll << 20);
  int force_slow = (ws_size < need) ? 1 : 0;
  unsigned* hb_fast = force_slow ? hb_safe
                                 : (unsigned*)(ws + (144ll << 20));  // 8 MB
  unsigned* xcdtab = (unsigned*)d_out;  // 512 words; overwritten by out_gemm

  // hb_safe and hb_fast are contiguous (136..152 MB): one sentinel sweep
  int hwords = (force_slow ? 1 : 2) * 2 * SEQ * HBW;
  init_sentinel<<<2048, 256, 0, stream>>>(hb_safe, hwords, xcdtab, 512);
  embed_pool<<<SEQ, 256, 0, stream>>>(emb, ids, seg, embeds);
  dim3 g2(G4H / 64, SEQ / 64, 2);
  xg_gemm<<<g2, 256, 0, stream>>>(embeds, w_ih_f, b_f, w_ih_b, b_b, xg);
  lstm_scan<<<2048, 64, 0, stream>>>(w_hh_f, w_hh_b, xg, hb_fast, hb_safe,
                                     xcdtab, force_slow);
  dim3 g4(TAGS / 128, SEQ / 64);
  out_gemm<<<g4, 256, 0, stream>>>(hb_fast, w_out, b_out, out);
  logsoftmax<<<SEQ, 256, 0, stream>>>(out);
}

// Round 16
// 11970.177 us; speedup vs baseline: 1.0129x; 1.0129x over previous
//
#include <hip/hip_runtime.h>
#include <hip/hip_bf16.h>

#define VOCAB 200000
#define EMB 256
#define HID 512
#define SEQ 8192
#define TOK 32768
#define TAGS 512
#define G4H 2048  // 4*HID
#define HBW 256   // h dwords per step per dir (packed bf16: 2 h per dword)

#define SENTP 0xFFFFFFFFu  // packed sentinel: bf16 NaN pair; finite h never produces it

typedef unsigned u2v __attribute__((ext_vector_type(2)));

__device__ __forceinline__ float sigmoidf_(float x) { return 1.0f / (1.0f + __expf(-x)); }
__device__ __forceinline__ float tanhf_(float x) { return 1.0f - 2.0f / (1.0f + __expf(2.0f * x)); }

__device__ __forceinline__ unsigned pack_bf16(float a, float b) {
  unsigned ua = __float_as_uint(a), ub = __float_as_uint(b);
  ua = (ua + 0x7FFFu + ((ua >> 16) & 1u)) >> 16;   // RNE
  ub = (ub + 0x7FFFu + ((ub >> 16) & 1u)) >> 16;
  return ua | (ub << 16);
}

// ------------- kernel 0: init (both h buffers + election table) --------------
__global__ void init_sentinel(unsigned* __restrict__ hbuf, int n,
                              unsigned* __restrict__ tab, int ntab) {
  int i = blockIdx.x * blockDim.x + threadIdx.x;
  int stride = gridDim.x * blockDim.x;
  for (int k = i; k < n; k += stride) hbuf[k] = SENTP;
  for (int k = i; k < ntab; k += stride) tab[k] = 0xFFFFFFFFu;
}

// ---------------- kernel 1: embedding bag (sum pool per sorted segment) ------
__global__ __launch_bounds__(256) void embed_pool(
    const float* __restrict__ emb, const int* __restrict__ ids,
    const int* __restrict__ seg, float* __restrict__ out) {
  int s = blockIdx.x;
  int d = threadIdx.x;  // 256 = EMB
  int lo = 0, hi = TOK;
  while (lo < hi) { int m = (lo + hi) >> 1; if (seg[m] < s) lo = m + 1; else hi = m; }
  int start = lo;
  hi = TOK;
  while (lo < hi) { int m = (lo + hi) >> 1; if (seg[m] < s + 1) lo = m + 1; else hi = m; }
  int end = lo;
  float acc = 0.f;
  for (int tkn = start; tkn < end; ++tkn) {
    acc += emb[(long)ids[tkn] * EMB + d];
  }
  out[s * EMB + d] = acc;
}

// ---------------- kernel 2: xg = embeds @ w_ih^T + b  (both dirs) ------------
__global__ __launch_bounds__(256) void xg_gemm(
    const float* __restrict__ embeds,
    const float* __restrict__ w_ih_f, const float* __restrict__ b_f,
    const float* __restrict__ w_ih_b, const float* __restrict__ b_b,
    float* __restrict__ xg) {
  int dir = blockIdx.z;
  const float* W = dir ? w_ih_b : w_ih_f;
  const float* B = dir ? b_b : b_f;
  float* out = xg + (size_t)dir * SEQ * G4H;
  int j0 = blockIdx.x * 64, t0 = blockIdx.y * 64;
  __shared__ float As[64][65];
  __shared__ float Bs[64][65];
  int tid = threadIdx.x;
  int ty = tid >> 4, tx = tid & 15;
  float acc[4][4] = {};
  for (int kc = 0; kc < EMB; kc += 64) {
#pragma unroll
    for (int i = 0; i < 4; ++i) {
      int fi = tid * 4 + i;
      int r = fi >> 4, c4 = fi & 15;
      float4 a = *(const float4*)&embeds[(size_t)(t0 + r) * EMB + kc + c4 * 4];
      As[r][c4 * 4 + 0] = a.x; As[r][c4 * 4 + 1] = a.y;
      As[r][c4 * 4 + 2] = a.z; As[r][c4 * 4 + 3] = a.w;
      float4 b = *(const float4*)&W[(size_t)(j0 + r) * EMB + kc + c4 * 4];
      Bs[r][c4 * 4 + 0] = b.x; Bs[r][c4 * 4 + 1] = b.y;
      Bs[r][c4 * 4 + 2] = b.z; Bs[r][c4 * 4 + 3] = b.w;
    }
    __syncthreads();
#pragma unroll 8
    for (int kk = 0; kk < 64; ++kk) {
      float a[4], b[4];
#pragma unroll
      for (int i = 0; i < 4; ++i) a[i] = As[ty * 4 + i][kk];
#pragma unroll
      for (int i = 0; i < 4; ++i) b[i] = Bs[tx * 4 + i][kk];
#pragma unroll
      for (int i = 0; i < 4; ++i)
#pragma unroll
        for (int j = 0; j < 4; ++j) acc[i][j] = fmaf(a[i], b[j], acc[i][j]);
    }
    __syncthreads();
  }
#pragma unroll
  for (int i = 0; i < 4; ++i)
#pragma unroll
    for (int j = 0; j < 4; ++j)
      out[(size_t)(t0 + ty * 4 + i) * G4H + j0 + tx * 4 + j] = acc[i][j] + B[j0 + tx * 4 + j];
}

// -- kernel 3: LSTM scan, sc1-L2 poll, packed-bf16 h, setprio compute burst ---
// Protocol/geometry = round 15 (proven). Single change: s_setprio(1) around
// the compute+publish burst (T5): poll-spinning waves run at prio 0, so a
// wave that HAS its data preempts its SIMD-mate that is merely polling --
// attacks the lockstep VALU-contention term identified in R14/R15.
__global__ __launch_bounds__(64) void lstm_scan(
    const float* __restrict__ w_hh_f, const float* __restrict__ w_hh_b,
    const float* __restrict__ xg, unsigned* __restrict__ hb_fast_base,
    unsigned* __restrict__ hb_safe_base, unsigned* __restrict__ xcdtab,
    int force_slow) {
  int b = blockIdx.x;
  int sel = b & 7;
  if (sel >= 2) return;  // non-worker block
  int dir = sel;
  int Wk = b >> 3;  // 0..255
  const float* W = dir ? w_hh_b : w_hh_f;
  const float* xgd = xg + (size_t)dir * SEQ * G4H;
  unsigned* hb_fast = hb_fast_base + (size_t)dir * SEQ * HBW;
  unsigned* hb_safe = hb_safe_base + (size_t)dir * SEQ * HBW;

  int lane = threadIdx.x;  // 0..63
  const int hh = lane & 1;
  const int k0 = 2 * Wk;

  // publish my XCD id (HW_REG_XCC_ID = hwreg 20)
  int my_xcd = (int)(__builtin_amdgcn_s_getreg(20 | (31 << 11)) & 0xFu);
  if (lane == 0)
    __hip_atomic_store(&xcdtab[dir * 256 + Wk], (unsigned)my_xcd,
                       __ATOMIC_RELAXED, __HIP_MEMORY_SCOPE_AGENT);

  // stage W slice in LDS: 8 rows x 512 cols f32 = 16KB
  __shared__ float4 Wl[8 * 128];  // f4 idx = r*128 + hf*64 + l
  for (int idx = lane; idx < 8 * 128; idx += 64) {
    int r = idx >> 7, c4 = idx & 127;
    int gr = 512 * (r >> 1) + k0 + (r & 1);
    Wl[idx] = *(const float4*)&W[(size_t)gr * HID + 4 * c4];
  }
  __syncthreads();

  // election read-back (symmetric verdict): 256 producers per direction
  bool same = false;
  if (!force_slow) {
    bool ok = true;
#pragma unroll
    for (int pp = 0; pp < 4; ++pp) {
      int p = lane + 64 * pp;
      unsigned v = 0xFFFFFFFFu;
      for (int tries = 0; tries < (1 << 15); ++tries) {
        v = __hip_atomic_load(&xcdtab[dir * 256 + p], __ATOMIC_RELAXED,
                              __HIP_MEMORY_SCOPE_AGENT);
        if (v != 0xFFFFFFFFu) break;
        __builtin_amdgcn_s_sleep(4);
      }
      ok &= (v == (unsigned)my_xcd);
    }
    same = __all((int)ok);
  }

  // prologue: xg for the first step (in registers at loop entry)
  int tt0 = dir ? (SEQ - 1) : 0;
  const float* xr0 = xgd + (size_t)tt0 * G4H + k0 + hh;
  float xv0 = xr0[0], xv1 = xr0[512], xv2 = xr0[1024], xv3 = xr0[1536];

  float cst = 0.f;  // cell state for h[k0+hh] (redundant across parity lanes)

  for (int t = 0; t < SEQ; ++t) {
    int tt = dir ? (SEQ - 1 - t) : t;
    int pt = dir ? (tt + 1) : (tt - 1);
    unsigned* srcF = hb_fast + (size_t)pt * HBW + 2 * lane;

    // A. issue first fast-poll sample before anything else
    u2v pa, pc;
    bool fastpoll = (t > 0) && same;
    if (fastpoll) {
      asm volatile(
          "global_load_dwordx2 %0, %2, off sc1\n\t"
          "global_load_dwordx2 %1, %2, off offset:512 sc1"
          : "=&v"(pa), "=&v"(pc)
          : "v"(srcF)
          : "memory");
    }

    // B. weight slice reads (LDS; independent of h; overlap poll RTT)
    float4 wl0[8], wl1[8];
#pragma unroll
    for (int r = 0; r < 8; ++r) {
      wl0[r] = Wl[r * 128 + lane];
      wl1[r] = Wl[r * 128 + 64 + lane];
    }

    // C. resolve h_prev (packed dwords d0..d3); polls run at prio 0
    unsigned d0, d1, d2, d3;
    if (t == 0) {
      d0 = d1 = d2 = d3 = 0u;  // bf16 pair (0,0)
    } else {
      if (fastpoll) {
        asm volatile("s_waitcnt vmcnt(0)" : "+v"(pa), "+v"(pc) :: "memory");
        __builtin_amdgcn_sched_barrier(0);
        d0 = pa.x; d1 = pa.y; d2 = pc.x; d3 = pc.y;
        bool ok = (d0 != SENTP) & (d1 != SENTP) & (d2 != SENTP) & (d3 != SENTP);
        bool got = __all((int)ok);
        for (int tries = 0; !got; ++tries) {
          u2v a, c;
          asm volatile(
              "global_load_dwordx2 %0, %2, off sc1\n\t"
              "global_load_dwordx2 %1, %2, off offset:512 sc1\n\t"
              "s_waitcnt vmcnt(0)"
              : "=&v"(a), "=&v"(c)
              : "v"(srcF)
              : "memory");
          __builtin_amdgcn_sched_barrier(0);
          d0 = a.x; d1 = a.y; d2 = c.x; d3 = c.y;
          ok = (d0 != SENTP) & (d1 != SENTP) & (d2 != SENTP) & (d3 != SENTP);
          got = __all((int)ok);
          if (!got && tries > 64) __builtin_amdgcn_s_sleep(2);
        }
      } else {
        unsigned* src = hb_safe + (size_t)pt * HBW + 2 * lane;
        for (;;) {
          u2v a, c;
          asm volatile(
              "global_load_dwordx2 %0, %2, off sc0 sc1\n\t"
              "global_load_dwordx2 %1, %2, off offset:512 sc0 sc1\n\t"
              "s_waitcnt vmcnt(0)"
              : "=&v"(a), "=&v"(c)
              : "v"(src)
              : "memory");
          __builtin_amdgcn_sched_barrier(0);
          d0 = a.x; d1 = a.y; d2 = c.x; d3 = c.y;
          bool ok = (d0 != SENTP) & (d1 != SENTP) & (d2 != SENTP) & (d3 != SENTP);
          if (__all((int)ok)) break;
          __builtin_amdgcn_s_sleep(1);
        }
      }
    }

    // ---- compute + publish burst at raised priority (T5) ----
    __builtin_amdgcn_s_setprio(1);

    // unpack: low half = even col, high half = odd col (exact bf16->f32)
    float4 h0, h1;
    h0.x = __uint_as_float(d0 << 16);
    h0.y = __uint_as_float(d0 & 0xFFFF0000u);
    h0.z = __uint_as_float(d1 << 16);
    h0.w = __uint_as_float(d1 & 0xFFFF0000u);
    h1.x = __uint_as_float(d2 << 16);
    h1.y = __uint_as_float(d2 & 0xFFFF0000u);
    h1.z = __uint_as_float(d3 << 16);
    h1.w = __uint_as_float(d3 & 0xFFFF0000u);

    // D. prefetch next step's xg (outside every poll's vmcnt window)
    int tn = (t + 1 < SEQ) ? (t + 1) : t;
    int ttn = dir ? (SEQ - 1 - tn) : tn;
    const float* xrn = xgd + (size_t)ttn * G4H + k0 + hh;
    float nx0 = xrn[0], nx1 = xrn[512], nx2 = xrn[1024], nx3 = xrn[1536];

    // E. matvec partials: acc[r] = sum over my 8 cols of W[r][c]*h[c]
    float acc[8];
#pragma unroll
    for (int r = 0; r < 8; ++r) {
      float4 wa = wl0[r];
      float4 wc = wl1[r];
      float a_ = wa.x * h0.x;
      a_ = fmaf(wa.y, h0.y, a_);
      a_ = fmaf(wa.z, h0.z, a_);
      a_ = fmaf(wa.w, h0.w, a_);
      a_ = fmaf(wc.x, h1.x, a_);
      a_ = fmaf(wc.y, h1.y, a_);
      a_ = fmaf(wc.z, h1.z, a_);
      a_ = fmaf(wc.w, h1.w, a_);
      acc[r] = a_;
    }

    // log-fold: 3 fold stages (xor1,2,4) + 3 butterflies (xor8,16,32)
    float v4[4];
    {
      int b0 = lane & 1;
#pragma unroll
      for (int j = 0; j < 4; ++j) {
        float mine = b0 ? acc[2 * j + 1] : acc[2 * j];
        float oth  = b0 ? acc[2 * j] : acc[2 * j + 1];
        v4[j] = mine + __shfl_xor(oth, 1);
      }
    }
    float v2[2];
    {
      int b1 = (lane >> 1) & 1;
#pragma unroll
      for (int j = 0; j < 2; ++j) {
        float mine = b1 ? v4[2 * j + 1] : v4[2 * j];
        float oth  = b1 ? v4[2 * j] : v4[2 * j + 1];
        v2[j] = mine + __shfl_xor(oth, 2);
      }
    }
    float v1;
    {
      int b2 = (lane >> 2) & 1;
      float mine = b2 ? v2[1] : v2[0];
      float oth  = b2 ? v2[0] : v2[1];
      v1 = mine + __shfl_xor(oth, 4);
      v1 += __shfl_xor(v1, 8);
      v1 += __shfl_xor(v1, 16);
      v1 += __shfl_xor(v1, 32);
    }

    // gather the 4 gate sums for my hh (row 2g+hh lives in lane 2g+hh)
    float si = __shfl(v1, hh + 0) + xv0;
    float sf = __shfl(v1, hh + 2) + xv1;
    float sg = __shfl(v1, hh + 4) + xv2;
    float so = __shfl(v1, hh + 6) + xv3;

    float iv = sigmoidf_(si), fv = sigmoidf_(sf), gv = tanhf_(sg), ov = sigmoidf_(so);
    cst = fv * cst + iv * gv;
    float h = ov * tanhf_(cst);

    // pack both h of this WG into one dword; lane 0 stores it
    float hodd = __shfl(h, 1);   // lane 1's value (hh=1)
    if (lane == 0) {
      unsigned packed = pack_bf16(h, hodd);
      hb_fast[(size_t)tt * HBW + Wk] = packed;        // plain -> local L2
      if (!same)
        __hip_atomic_store(hb_safe + (size_t)tt * HBW + Wk, packed,
                           __ATOMIC_RELAXED, __HIP_MEMORY_SCOPE_AGENT);
    }
    __builtin_amdgcn_s_setprio(0);

    xv0 = nx0; xv1 = nx1; xv2 = nx2; xv3 = nx3;
  }
}

// ---------------- kernel 4: logits = h_cat @ w_out^T + b_out -----------------
// hbuf is packed bf16: [dir][SEQ][256] dwords (2 h per dword)
__global__ __launch_bounds__(256) void out_gemm(
    const unsigned* __restrict__ hbuf, const float* __restrict__ w_out,
    const float* __restrict__ b_out, float* __restrict__ out) {
  int j0 = blockIdx.x * 128, t0 = blockIdx.y * 64;
  __shared__ float hs[64][65];
  __shared__ float ws_[128][65];
  int tid = threadIdx.x;
  int ti = tid & 15, ji = tid >> 4;
  float acc[4][8] = {};
  for (int kc = 0; kc < 1024; kc += 64) {
    const unsigned* hsrc = (kc < 512) ? hbuf : (hbuf + (size_t)SEQ * HBW);
    int kbd = (kc & 511) >> 1;  // dword offset in row
#pragma unroll
    for (int j = 0; j < 8; ++j) {
      int idx = j * 256 + tid;        // 0..2047
      int r = idx >> 5, dw = idx & 31;
      unsigned u = hsrc[(size_t)(t0 + r) * HBW + kbd + dw];
      hs[r][dw * 2 + 0] = __uint_as_float(u << 16);
      hs[r][dw * 2 + 1] = __uint_as_float(u & 0xFFFF0000u);
    }
#pragma unroll
    for (int i = 0; i < 8; ++i) {
      int fi = tid * 8 + i;
      int r = fi >> 4, c4 = fi & 15;
      float4 v = *(const float4*)&w_out[(size_t)(j0 + r) * 1024 + kc + c4 * 4];
      ws_[r][c4 * 4 + 0] = v.x; ws_[r][c4 * 4 + 1] = v.y;
      ws_[r][c4 * 4 + 2] = v.z; ws_[r][c4 * 4 + 3] = v.w;
    }
    __syncthreads();
#pragma unroll 4
    for (int kk = 0; kk < 64; ++kk) {
      float a[4], b[8];
#pragma unroll
      for (int x = 0; x < 4; ++x) a[x] = hs[ti * 4 + x][kk];
#pragma unroll
      for (int y = 0; y < 8; ++y) b[y] = ws_[ji * 8 + y][kk];
#pragma unroll
      for (int x = 0; x < 4; ++x)
#pragma unroll
        for (int y = 0; y < 8; ++y) acc[x][y] = fmaf(a[x], b[y], acc[x][y]);
    }
    __syncthreads();
  }
#pragma unroll
  for (int x = 0; x < 4; ++x)
#pragma unroll
    for (int y = 0; y < 8; ++y)
      out[(size_t)(t0 + ti * 4 + x) * TAGS + j0 + ji * 8 + y] = acc[x][y] + b_out[j0 + ji * 8 + y];
}

// ---------------- kernel 5: row-wise log_softmax in place --------------------
__global__ __launch_bounds__(256) void logsoftmax(float* __restrict__ out) {
  int t = blockIdx.x;
  float* row = out + (size_t)t * TAGS;
  int tid = threadIdx.x;
  float a = row[tid], b = row[tid + 256];
  float m = fmaxf(a, b);
  m = fmaxf(m, __shfl_xor(m, 1));
  m = fmaxf(m, __shfl_xor(m, 2));
  m = fmaxf(m, __shfl_xor(m, 4));
  m = fmaxf(m, __shfl_xor(m, 8));
  m = fmaxf(m, __shfl_xor(m, 16));
  m = fmaxf(m, __shfl_xor(m, 32));
  __shared__ float redm[4];
  __shared__ float reds[4];
  int wv = tid >> 6;
  if ((tid & 63) == 0) redm[wv] = m;
  __syncthreads();
  m = fmaxf(fmaxf(redm[0], redm[1]), fmaxf(redm[2], redm[3]));
  float s = __expf(a - m) + __expf(b - m);
  s += __shfl_xor(s, 1);
  s += __shfl_xor(s, 2);
  s += __shfl_xor(s, 4);
  s += __shfl_xor(s, 8);
  s += __shfl_xor(s, 16);
  s += __shfl_xor(s, 32);
  if ((tid & 63) == 0) reds[wv] = s;
  __syncthreads();
  s = reds[0] + reds[1] + reds[2] + reds[3];
  float ls = m + __logf(s);
  row[tid] = a - ls;
  row[tid + 256] = b - ls;
}

extern "C" void kernel_launch(void* const* d_in, const int* in_sizes, int n_in,
                              void* d_out, int out_size, void* d_ws, size_t ws_size,
                              hipStream_t stream) {
  (void)in_sizes; (void)n_in; (void)out_size;
  const float* emb    = (const float*)d_in[0];
  const float* w_ih_f = (const float*)d_in[1];
  const float* w_hh_f = (const float*)d_in[2];
  const float* b_f    = (const float*)d_in[3];
  const float* w_ih_b = (const float*)d_in[4];
  const float* w_hh_b = (const float*)d_in[5];
  const float* b_b    = (const float*)d_in[6];
  const float* w_out  = (const float*)d_in[7];
  const float* b_out  = (const float*)d_in[8];
  const int*   ids    = (const int*)d_in[9];
  const int*   seg    = (const int*)d_in[10];
  float* out = (float*)d_out;

  char* ws = (char*)d_ws;
  float*    embeds  = (float*)ws;                                  // 8 MB
  float*    xg      = (float*)(ws + (8ll << 20));                  // 128 MB
  unsigned* hb_safe = (unsigned*)(ws + (136ll << 20));             // 8 MB (packed)
  size_t need = (152ll << 20);
  int force_slow = (ws_size < need) ? 1 : 0;
  unsigned* hb_fast = force_slow ? hb_safe
                                 : (unsigned*)(ws + (144ll << 20));  // 8 MB
  unsigned* xcdtab = (unsigned*)d_out;  // 512 words; overwritten by out_gemm

  int hwords = (force_slow ? 1 : 2) * 2 * SEQ * HBW;
  init_sentinel<<<2048, 256, 0, stream>>>(hb_safe, hwords, xcdtab, 512);
  embed_pool<<<SEQ, 256, 0, stream>>>(emb, ids, seg, embeds);
  dim3 g2(G4H / 64, SEQ / 64, 2);
  xg_gemm<<<g2, 256, 0, stream>>>(embeds, w_ih_f, b_f, w_ih_b, b_b, xg);
  lstm_scan<<<2048, 64, 0, stream>>>(w_hh_f, w_hh_b, xg, hb_fast, hb_safe,
                                     xcdtab, force_slow);
  dim3 g4(TAGS / 128, SEQ / 64);
  out_gemm<<<g4, 256, 0, stream>>>(hb_fast, w_out, b_out, out);
  logsoftmax<<<SEQ, 256, 0, stream>>>(out);
}